// Round 1
// baseline (68.518 us; speedup 1.0000x reference)
//
#include <hip/hip_runtime.h>
#include <math.h>

#define NW   21
#define EMB  256
#define LN_EPS 1e-5f

struct cpx { float re, im; };
__device__ inline cpx cmul(cpx a, cpx b){ return cpx{a.re*b.re - a.im*b.im, a.re*b.im + a.im*b.re}; }
__device__ inline cpx cadd(cpx a, cpx b){ return cpx{a.re+b.re, a.im+b.im}; }
__device__ inline cpx cscale(cpx a, float s){ return cpx{a.re*s, a.im*s}; }
__device__ inline cpx cexp_i(float t){ float s,c; sincosf(t,&s,&c); return cpx{c,s}; }

// One block per token. Threads 0..20 build gate constants in LDS; threads 0,1
// build the 13-wire (vocab-bit) transfer-matrix prefix for s=0,1; each of the
// 256 threads finishes its embed index e = tid (wires 13..20), then block LN.
__global__ __launch_bounds__(256) void qembed_fused(
    const int*   __restrict__ x,
    const float* __restrict__ rp1,
    const float* __restrict__ rp2,
    const float* __restrict__ gamma,
    const float* __restrict__ beta,
    float*       __restrict__ out)
{
    __shared__ cpx sA[NW][2];       // layer-1 column-0 amplitudes a_w[bit]
    __shared__ cpx sU[NW][2][2];    // layer-2 Rot matrices
    __shared__ cpx sPre[2][2];      // prefix vector per s
    __shared__ float sRed[8];

    const int tid = threadIdx.x;
    const int tok = blockIdx.x;

    if (tid < NW) {
        // layer 1: a[0] = exp(-i(phi+om)/2) cos(th/2); a[1] = exp(-i(phi-om)/2) sin(th/2)
        float p = rp1[tid*3+0], th = rp1[tid*3+1], om = rp1[tid*3+2];
        float st, ct; sincosf(0.5f*th, &st, &ct);
        cpx em = cexp_i(-0.5f*(p+om));
        cpx ed = cexp_i(-0.5f*(p-om));
        sA[tid][0] = cscale(em, ct);
        sA[tid][1] = cscale(ed, st);
        // layer 2 full matrix
        p = rp2[tid*3+0]; th = rp2[tid*3+1]; om = rp2[tid*3+2];
        sincosf(0.5f*th, &st, &ct);
        em = cexp_i(-0.5f*(p+om));   // u00 = em*ct ; u11 = conj(em)*ct
        ed = cexp_i(-0.5f*(p-om));   // u10 = ed*st ; u01 = -conj(ed)*st
        sU[tid][0][0] = cscale(em, ct);
        sU[tid][1][1] = cpx{ em.re*ct, -em.im*ct};
        sU[tid][1][0] = cscale(ed, st);
        sU[tid][0][1] = cpx{-ed.re*st,  ed.im*st};
    }
    __syncthreads();

    const int v = x[tok];   // vocab id -> wires 0..12 (MSB-first)

    if (tid < 2) {
        const int s = tid;  // loop-closure bit b'_20
        int n0 = (v >> 12) & 1;
        cpx w0 = cmul(sU[0][n0][0], sA[0][s]);
        cpx w1 = cmul(sU[0][n0][1], sA[0][1^s]);
        #pragma unroll
        for (int i = 1; i <= 12; ++i) {
            int ni = (v >> (12-i)) & 1;
            int sb = (i == 1) ? s : 0;
            cpx t0 = cadd(cmul(w0, sA[i][sb]),   cmul(w1, sA[i][1^sb]));
            cpx t1 = cadd(cmul(w0, sA[i][1^sb]), cmul(w1, sA[i][sb]));
            w0 = cmul(sU[i][ni][0], t0);
            w1 = cmul(sU[i][ni][1], t1);
        }
        sPre[s][0] = w0; sPre[s][1] = w1;
    }
    __syncthreads();

    const int e = tid;      // embed index -> wires 13..20
    cpx amp = cpx{0.f, 0.f};
    #pragma unroll
    for (int s = 0; s < 2; ++s) {
        cpx w0 = sPre[s][0], w1 = sPre[s][1];
        #pragma unroll
        for (int i = 13; i <= 19; ++i) {
            int ni = (e >> (20-i)) & 1;
            cpx t0 = cadd(cmul(w0, sA[i][0]), cmul(w1, sA[i][1]));
            cpx t1 = cadd(cmul(w0, sA[i][1]), cmul(w1, sA[i][0]));
            w0 = cmul(sU[i][ni][0], t0);
            w1 = cmul(sU[i][ni][1], t1);
        }
        int n20 = e & 1;
        cpx d = cadd(cmul(w0, sA[20][s]), cmul(w1, sA[20][1^s]));
        amp = cadd(amp, cmul(sU[20][n20][s], d));
    }
    float mag = sqrtf(amp.re*amp.re + amp.im*amp.im);

    // ---- LayerNorm over the 256 values of this block ----
    float sum = mag, sq = mag*mag;
    #pragma unroll
    for (int off = 32; off; off >>= 1) {
        sum += __shfl_down(sum, off);
        sq  += __shfl_down(sq,  off);
    }
    const int wave = tid >> 6;
    if ((tid & 63) == 0) { sRed[wave] = sum; sRed[4+wave] = sq; }
    __syncthreads();
    sum = sRed[0] + sRed[1] + sRed[2] + sRed[3];
    sq  = sRed[4] + sRed[5] + sRed[6] + sRed[7];
    const float mu  = sum * (1.0f/EMB);
    float var = sq * (1.0f/EMB) - mu*mu;
    if (var < 0.f) var = 0.f;
    const float rs = 1.0f / sqrtf(var + LN_EPS);
    out[tok*EMB + e] = (mag - mu) * rs * gamma[e] + beta[e];
}

extern "C" void kernel_launch(void* const* d_in, const int* in_sizes, int n_in,
                              void* d_out, int out_size, void* d_ws, size_t ws_size,
                              hipStream_t stream) {
    const int*   x     = (const int*)  d_in[0];
    const float* rp1   = (const float*)d_in[1];
    const float* rp2   = (const float*)d_in[2];
    const float* gamma = (const float*)d_in[3];
    const float* beta  = (const float*)d_in[4];
    float* out = (float*)d_out;
    const int ntok = in_sizes[0];   // B*S = 16384
    qembed_fused<<<ntok, 256, 0, stream>>>(x, rp1, rp2, gamma, beta, out);
}

// Round 2
// 25.930 us; speedup vs baseline: 2.6424x; 2.6424x over previous
//
#include <hip/hip_runtime.h>
#include <math.h>

#define NW     21
#define EMB    256
#define VOCAB  8192
#define LN_EPS 1e-5f

struct cpx { float re, im; };
__device__ inline cpx cmul(cpx a, cpx b){ return cpx{a.re*b.re - a.im*b.im, a.re*b.im + a.im*b.re}; }
__device__ inline cpx cadd(cpx a, cpx b){ return cpx{a.re+b.re, a.im+b.im}; }
__device__ inline cpx cscale(cpx a, float s){ return cpx{a.re*s, a.im*s}; }
__device__ inline cpx cexp_i(float t){ float s,c; sincosf(t,&s,&c); return cpx{c,s}; }

// ---------------------------------------------------------------------------
// Setup: blocks 0..31 build P[v][s][j] (prefix transfer vectors, 8192 x 4 cpx),
// block 32 builds S[e][s][j] (suffix basis responses, 256 x 4 cpx).
// amp(v,e) = sum_{s,j} P[v][s][j] * S[e][s][j]
// ---------------------------------------------------------------------------
__global__ __launch_bounds__(256) void qembed_setup(
    const float* __restrict__ rp1,
    const float* __restrict__ rp2,
    float* __restrict__ Ptab,    // 8192*8 floats
    float* __restrict__ Stab)    // 256*8 floats
{
    __shared__ cpx sA[NW][2];       // layer-1 column-0 amplitudes
    __shared__ cpx sU[NW][2][2];    // layer-2 Rot matrices
    const int tid = threadIdx.x;

    if (tid < NW) {
        float p = rp1[tid*3+0], th = rp1[tid*3+1], om = rp1[tid*3+2];
        float st, ct; sincosf(0.5f*th, &st, &ct);
        cpx em = cexp_i(-0.5f*(p+om));
        cpx ed = cexp_i(-0.5f*(p-om));
        sA[tid][0] = cscale(em, ct);
        sA[tid][1] = cscale(ed, st);
        p = rp2[tid*3+0]; th = rp2[tid*3+1]; om = rp2[tid*3+2];
        sincosf(0.5f*th, &st, &ct);
        em = cexp_i(-0.5f*(p+om));
        ed = cexp_i(-0.5f*(p-om));
        sU[tid][0][0] = cscale(em, ct);
        sU[tid][1][1] = cpx{ em.re*ct, -em.im*ct};
        sU[tid][1][0] = cscale(ed, st);
        sU[tid][0][1] = cpx{-ed.re*st,  ed.im*st};
    }
    __syncthreads();

    if (blockIdx.x < 32) {
        const int v = blockIdx.x*256 + tid;
        float4 res[2];
        #pragma unroll
        for (int s = 0; s < 2; ++s) {
            int n0 = (v >> 12) & 1;
            cpx w0 = cmul(sU[0][n0][0], sA[0][s]);
            cpx w1 = cmul(sU[0][n0][1], sA[0][1^s]);
            #pragma unroll
            for (int i = 1; i <= 12; ++i) {
                int ni = (v >> (12-i)) & 1;
                int sb = (i == 1) ? s : 0;
                cpx t0 = cadd(cmul(w0, sA[i][sb]),   cmul(w1, sA[i][1^sb]));
                cpx t1 = cadd(cmul(w0, sA[i][1^sb]), cmul(w1, sA[i][sb]));
                w0 = cmul(sU[i][ni][0], t0);
                w1 = cmul(sU[i][ni][1], t1);
            }
            res[s] = make_float4(w0.re, w0.im, w1.re, w1.im);
        }
        float4* P4 = (float4*)(Ptab + v*8);
        P4[0] = res[0];
        P4[1] = res[1];
    } else {
        const int e = tid;
        cpx M[2][2];    // M[row][basis j] after wires 13..19
        #pragma unroll
        for (int j = 0; j < 2; ++j) {
            cpx w0 = (j == 0) ? cpx{1.f,0.f} : cpx{0.f,0.f};
            cpx w1 = (j == 0) ? cpx{0.f,0.f} : cpx{1.f,0.f};
            #pragma unroll
            for (int i = 13; i <= 19; ++i) {
                int ni = (e >> (20-i)) & 1;
                cpx t0 = cadd(cmul(w0, sA[i][0]), cmul(w1, sA[i][1]));
                cpx t1 = cadd(cmul(w0, sA[i][1]), cmul(w1, sA[i][0]));
                w0 = cmul(sU[i][ni][0], t0);
                w1 = cmul(sU[i][ni][1], t1);
            }
            M[0][j] = w0; M[1][j] = w1;
        }
        const int n20 = e & 1;
        float o8[8];
        #pragma unroll
        for (int s = 0; s < 2; ++s) {
            #pragma unroll
            for (int j = 0; j < 2; ++j) {
                cpx d = cadd(cmul(M[0][j], sA[20][s]), cmul(M[1][j], sA[20][1^s]));
                cpx S = cmul(sU[20][n20][s], d);
                o8[s*4 + j*2 + 0] = S.re;
                o8[s*4 + j*2 + 1] = S.im;
            }
        }
        float4* S4 = (float4*)(Stab + e*8);
        S4[0] = *(float4*)&o8[0];
        S4[1] = *(float4*)&o8[4];
    }
}

// ---------------------------------------------------------------------------
// Main: one wave per token-group. Lane l owns e = 4l..4l+3 (S rows + gamma/beta
// register-resident across the token loop). LN via wave64 butterfly — no LDS.
// ---------------------------------------------------------------------------
__global__ __launch_bounds__(256) void qembed_main(
    const int*   __restrict__ x,
    const float* __restrict__ Ptab,
    const float* __restrict__ Stab,
    const float* __restrict__ gamma,
    const float* __restrict__ beta,
    float*       __restrict__ out,
    int ntok, int tokPerWave)
{
    const int tid   = threadIdx.x;
    const int lane  = tid & 63;
    const int gwave = blockIdx.x*4 + (tid >> 6);
    const int e0    = lane*4;

    float4 s0[4], s1[4];
    #pragma unroll
    for (int k = 0; k < 4; ++k) {
        const float4* S4 = (const float4*)(Stab + (e0+k)*8);
        s0[k] = S4[0]; s1[k] = S4[1];
    }
    const float4 g4 = *(const float4*)(gamma + e0);
    const float4 b4 = *(const float4*)(beta  + e0);

    for (int t = 0; t < tokPerWave; ++t) {
        const int tok = gwave*tokPerWave + t;
        if (tok >= ntok) break;
        const int v = x[tok];
        const float4* P4 = (const float4*)(Ptab + v*8);
        const float4 p0 = P4[0], p1 = P4[1];

        float mags[4];
        float lsum = 0.f, lsq = 0.f;
        #pragma unroll
        for (int k = 0; k < 4; ++k) {
            float re, im;
            re  = p0.x*s0[k].x - p0.y*s0[k].y;
            im  = p0.x*s0[k].y + p0.y*s0[k].x;
            re += p0.z*s0[k].z - p0.w*s0[k].w;
            im += p0.z*s0[k].w + p0.w*s0[k].z;
            re += p1.x*s1[k].x - p1.y*s1[k].y;
            im += p1.x*s1[k].y + p1.y*s1[k].x;
            re += p1.z*s1[k].z - p1.w*s1[k].w;
            im += p1.z*s1[k].w + p1.w*s1[k].z;
            const float m = sqrtf(re*re + im*im);
            mags[k] = m; lsum += m; lsq += m*m;
        }
        #pragma unroll
        for (int off = 32; off; off >>= 1) {
            lsum += __shfl_xor(lsum, off);
            lsq  += __shfl_xor(lsq,  off);
        }
        const float mu = lsum * (1.0f/EMB);
        float var = lsq * (1.0f/EMB) - mu*mu;
        if (var < 0.f) var = 0.f;
        const float rs = 1.0f / sqrtf(var + LN_EPS);

        float4 o;
        o.x = (mags[0]-mu)*rs*g4.x + b4.x;
        o.y = (mags[1]-mu)*rs*g4.y + b4.y;
        o.z = (mags[2]-mu)*rs*g4.z + b4.z;
        o.w = (mags[3]-mu)*rs*g4.w + b4.w;
        *(float4*)(out + tok*EMB + e0) = o;
    }
}

extern "C" void kernel_launch(void* const* d_in, const int* in_sizes, int n_in,
                              void* d_out, int out_size, void* d_ws, size_t ws_size,
                              hipStream_t stream) {
    const int*   x     = (const int*)  d_in[0];
    const float* rp1   = (const float*)d_in[1];
    const float* rp2   = (const float*)d_in[2];
    const float* gamma = (const float*)d_in[3];
    const float* beta  = (const float*)d_in[4];
    float* out = (float*)d_out;
    const int ntok = in_sizes[0];        // B*S = 16384

    float* Ptab = (float*)d_ws;          // 8192*8 floats = 256 KB
    float* Stab = Ptab + VOCAB*8;        // 256*8 floats  = 8 KB

    qembed_setup<<<33, 256, 0, stream>>>(rp1, rp2, Ptab, Stab);

    const int blocks     = 1024;                       // 4 waves each
    const int totalWaves = blocks*4;
    const int tokPerWave = (ntok + totalWaves - 1) / totalWaves;
    qembed_main<<<blocks, 256, 0, stream>>>(x, Ptab, Stab, gamma, beta,
                                            out, ntok, tokPerWave);
}

// Round 3
// 20.363 us; speedup vs baseline: 3.3649x; 1.2734x over previous
//
#include <hip/hip_runtime.h>
#include <math.h>

#define NW     21
#define EMB    256
#define TPW    8          // tokens per wave
#define LN_EPS 1e-5f

struct cpx { float re, im; };
__device__ inline cpx cmul(cpx a, cpx b){ return cpx{a.re*b.re - a.im*b.im, a.re*b.im + a.im*b.re}; }
__device__ inline cpx cadd(cpx a, cpx b){ return cpx{a.re+b.re, a.im+b.im}; }
__device__ inline cpx cscale(cpx a, float s){ return cpx{a.re*s, a.im*s}; }
__device__ inline cpx cexp_i(float t){ float s,c; sincosf(t,&s,&c); return cpx{c,s}; }

// Single fused kernel. Per block (256 thr = 4 waves, 32 tokens):
//  phase 0: lanes<21 build gate constants (sA layer-1 col-0, sU layer-2) in LDS
//  phase 1: thread e=tid runs the suffix chain (wires 13..20 basis responses)
//           -> sSt[8][256] component-major (conflict-free b128 reads later);
//           lanes 0..15 of each wave run the 8-token x 2-s prefix chains
//           (wires 0..12, vocab bits) in parallel -> sP4[wave][tok][s]
//  phase 2: token loop: amp = <P[v], S[e]> (length-4 complex dot),
//           LayerNorm via wave64 butterfly, float4 store. No global gather.
__global__ __launch_bounds__(256) void qembed_one(
    const int*   __restrict__ x,
    const float* __restrict__ rp1,
    const float* __restrict__ rp2,
    const float* __restrict__ gamma,
    const float* __restrict__ beta,
    float*       __restrict__ out,
    int ntok)
{
    __shared__ cpx    sA[NW][2];
    __shared__ cpx    sU[NW][2][2];
    __shared__ float  sSt[8][EMB];       // S components, component-major
    __shared__ float4 sP4[4][TPW][2];    // per-wave prefix vectors

    const int tid   = threadIdx.x;
    const int lane  = tid & 63;
    const int wv    = tid >> 6;
    const int e0    = lane * 4;
    const int wbase = (blockIdx.x * 4 + wv) * TPW;

    const float4 g4 = *(const float4*)(gamma + e0);
    const float4 b4 = *(const float4*)(beta  + e0);

    if (tid < NW) {
        float p = rp1[tid*3+0], th = rp1[tid*3+1], om = rp1[tid*3+2];
        float st, ct; sincosf(0.5f*th, &st, &ct);
        cpx em = cexp_i(-0.5f*(p+om));
        cpx ed = cexp_i(-0.5f*(p-om));
        sA[tid][0] = cscale(em, ct);
        sA[tid][1] = cscale(ed, st);
        p = rp2[tid*3+0]; th = rp2[tid*3+1]; om = rp2[tid*3+2];
        sincosf(0.5f*th, &st, &ct);
        em = cexp_i(-0.5f*(p+om));
        ed = cexp_i(-0.5f*(p-om));
        sU[tid][0][0] = cscale(em, ct);
        sU[tid][1][1] = cpx{ em.re*ct, -em.im*ct};
        sU[tid][1][0] = cscale(ed, st);
        sU[tid][0][1] = cpx{-ed.re*st,  ed.im*st};
    }
    __syncthreads();

    // ---- suffix basis chain for e = tid ----
    {
        const int e = tid;
        cpx M[2][2];
        #pragma unroll
        for (int j = 0; j < 2; ++j) {
            cpx w0 = (j == 0) ? cpx{1.f,0.f} : cpx{0.f,0.f};
            cpx w1 = (j == 0) ? cpx{0.f,0.f} : cpx{1.f,0.f};
            #pragma unroll
            for (int i = 13; i <= 19; ++i) {
                int ni = (e >> (20-i)) & 1;
                cpx t0 = cadd(cmul(w0, sA[i][0]), cmul(w1, sA[i][1]));
                cpx t1 = cadd(cmul(w0, sA[i][1]), cmul(w1, sA[i][0]));
                w0 = cmul(sU[i][ni][0], t0);
                w1 = cmul(sU[i][ni][1], t1);
            }
            M[0][j] = w0; M[1][j] = w1;
        }
        const int n20 = e & 1;
        float o8[8];
        #pragma unroll
        for (int s = 0; s < 2; ++s) {
            #pragma unroll
            for (int j = 0; j < 2; ++j) {
                cpx d = cadd(cmul(M[0][j], sA[20][s]), cmul(M[1][j], sA[20][1^s]));
                cpx S = cmul(sU[20][n20][s], d);
                o8[s*4 + j*2 + 0] = S.re;
                o8[s*4 + j*2 + 1] = S.im;
            }
        }
        #pragma unroll
        for (int c = 0; c < 8; ++c) sSt[c][e] = o8[c];
    }

    // ---- prefix chains: lanes 0..15 handle (token k, closure-bit s) ----
    if (lane < 16) {
        const int k = lane >> 1, s = lane & 1;
        const int tk = wbase + k;
        const int v = (tk < ntok) ? x[tk] : 0;
        int n0 = (v >> 12) & 1;
        cpx w0 = cmul(sU[0][n0][0], sA[0][s]);
        cpx w1 = cmul(sU[0][n0][1], sA[0][1^s]);
        #pragma unroll
        for (int i = 1; i <= 12; ++i) {
            int ni = (v >> (12-i)) & 1;
            int sb = (i == 1) ? s : 0;
            cpx t0 = cadd(cmul(w0, sA[i][sb]),   cmul(w1, sA[i][1^sb]));
            cpx t1 = cadd(cmul(w0, sA[i][1^sb]), cmul(w1, sA[i][sb]));
            w0 = cmul(sU[i][ni][0], t0);
            w1 = cmul(sU[i][ni][1], t1);
        }
        sP4[wv][k][s] = make_float4(w0.re, w0.im, w1.re, w1.im);
    }
    __syncthreads();

    // ---- register-load S components for this lane's 4 e's (conflict-free) ----
    float sr[8][4];
    #pragma unroll
    for (int c = 0; c < 8; ++c) {
        float4 t = *(const float4*)&sSt[c][e0];
        sr[c][0] = t.x; sr[c][1] = t.y; sr[c][2] = t.z; sr[c][3] = t.w;
    }

    // ---- token loop ----
    #pragma unroll 2
    for (int t = 0; t < TPW; ++t) {
        const int tok = wbase + t;
        const float4 p0 = sP4[wv][t][0];
        const float4 p1 = sP4[wv][t][1];

        float mags[4];
        float lsum = 0.f, lsq = 0.f;
        #pragma unroll
        for (int k = 0; k < 4; ++k) {
            float re = p0.x*sr[0][k] - p0.y*sr[1][k]
                     + p0.z*sr[2][k] - p0.w*sr[3][k]
                     + p1.x*sr[4][k] - p1.y*sr[5][k]
                     + p1.z*sr[6][k] - p1.w*sr[7][k];
            float im = p0.x*sr[1][k] + p0.y*sr[0][k]
                     + p0.z*sr[3][k] + p0.w*sr[2][k]
                     + p1.x*sr[5][k] + p1.y*sr[4][k]
                     + p1.z*sr[7][k] + p1.w*sr[6][k];
            const float m = sqrtf(re*re + im*im);
            mags[k] = m; lsum += m; lsq += m*m;
        }
        #pragma unroll
        for (int off = 32; off; off >>= 1) {
            lsum += __shfl_xor(lsum, off);
            lsq  += __shfl_xor(lsq,  off);
        }
        const float mu = lsum * (1.0f/EMB);
        float var = lsq * (1.0f/EMB) - mu*mu;
        if (var < 0.f) var = 0.f;
        const float rs = 1.0f / sqrtf(var + LN_EPS);

        if (tok < ntok) {
            float4 o;
            o.x = (mags[0]-mu)*rs*g4.x + b4.x;
            o.y = (mags[1]-mu)*rs*g4.y + b4.y;
            o.z = (mags[2]-mu)*rs*g4.z + b4.z;
            o.w = (mags[3]-mu)*rs*g4.w + b4.w;
            *(float4*)(out + tok*EMB + e0) = o;
        }
    }
}

extern "C" void kernel_launch(void* const* d_in, const int* in_sizes, int n_in,
                              void* d_out, int out_size, void* d_ws, size_t ws_size,
                              hipStream_t stream) {
    const int*   x     = (const int*)  d_in[0];
    const float* rp1   = (const float*)d_in[1];
    const float* rp2   = (const float*)d_in[2];
    const float* gamma = (const float*)d_in[3];
    const float* beta  = (const float*)d_in[4];
    float* out = (float*)d_out;
    const int ntok = in_sizes[0];                  // B*S = 16384
    const int tokPerBlock = 4 * TPW;               // 4 waves x 8 tokens
    const int nblocks = (ntok + tokPerBlock - 1) / tokPerBlock;
    qembed_one<<<nblocks, 256, 0, stream>>>(x, rp1, rp2, gamma, beta, out, ntok);
}

// Round 4
// 17.889 us; speedup vs baseline: 3.8302x; 1.1383x over previous
//
#include <hip/hip_runtime.h>
#include <math.h>

#define NW     21
#define EMB    256
#define LN_EPS 1e-5f

struct cpx { float re, im; };
__device__ inline cpx cmul(cpx a, cpx b){ return cpx{a.re*b.re - a.im*b.im, a.re*b.im + a.im*b.re}; }
__device__ inline cpx cadd(cpx a, cpx b){ return cpx{a.re+b.re, a.im+b.im}; }
__device__ inline cpx cscale(cpx a, float s){ return cpx{a.re*s, a.im*s}; }
__device__ inline cpx cexp_i(float t){ float s,c; sincosf(t,&s,&c); return cpx{c,s}; }

// One kernel, 512 threads (8 waves), 32 tokens per block (4 per wave).
//  phase 0: tid<21 builds gate constants in LDS
//  phase 1: waves 0-3 (tid<256): suffix chain for e=tid -> sSt[8][256]
//           wave 4 (tid 256..319): all 64 prefix chains (32 tok x 2 s) -> sP4
//           waves 5-7: free
//  phase 2: each wave: 4 tokens. Compute ALL mags first (registers), then a
//           batched 6-level butterfly (8 independent chains -> latency hidden),
//           then 4 epilogues + float4 stores.
__global__ __launch_bounds__(512, 4) void qembed_one(
    const int*   __restrict__ x,
    const float* __restrict__ rp1,
    const float* __restrict__ rp2,
    const float* __restrict__ gamma,
    const float* __restrict__ beta,
    float*       __restrict__ out,
    int ntok)
{
    __shared__ cpx    sA[NW][2];
    __shared__ cpx    sU[NW][2][2];
    __shared__ float  sSt[8][EMB];       // suffix components, component-major
    __shared__ float4 sP4[32][2];        // per-block prefix vectors

    const int tid      = threadIdx.x;
    const int lane     = tid & 63;
    const int wv       = tid >> 6;       // 0..7
    const int e0       = lane * 4;
    const int blockTok = blockIdx.x * 32;

    // hoist global loads (latency hides under gate build + barrier)
    const float4 g4 = *(const float4*)(gamma + e0);
    const float4 b4 = *(const float4*)(beta  + e0);
    int pv = 0;
    if (wv == 4) {
        int k = lane >> 1;
        int idx = blockTok + k;
        if (idx >= ntok) idx = ntok - 1;
        pv = x[idx];
    }

    if (tid < NW) {
        float p = rp1[tid*3+0], th = rp1[tid*3+1], om = rp1[tid*3+2];
        float st, ct; sincosf(0.5f*th, &st, &ct);
        cpx em = cexp_i(-0.5f*(p+om));
        cpx ed = cexp_i(-0.5f*(p-om));
        sA[tid][0] = cscale(em, ct);
        sA[tid][1] = cscale(ed, st);
        p = rp2[tid*3+0]; th = rp2[tid*3+1]; om = rp2[tid*3+2];
        sincosf(0.5f*th, &st, &ct);
        em = cexp_i(-0.5f*(p+om));
        ed = cexp_i(-0.5f*(p-om));
        sU[tid][0][0] = cscale(em, ct);
        sU[tid][1][1] = cpx{ em.re*ct, -em.im*ct};
        sU[tid][1][0] = cscale(ed, st);
        sU[tid][0][1] = cpx{-ed.re*st,  ed.im*st};
    }
    __syncthreads();

    if (tid < 256) {
        // ---- suffix basis chain for e = tid ----
        const int e = tid;
        cpx M[2][2];
        #pragma unroll
        for (int j = 0; j < 2; ++j) {
            cpx w0 = (j == 0) ? cpx{1.f,0.f} : cpx{0.f,0.f};
            cpx w1 = (j == 0) ? cpx{0.f,0.f} : cpx{1.f,0.f};
            #pragma unroll
            for (int i = 13; i <= 19; ++i) {
                int ni = (e >> (20-i)) & 1;
                cpx t0 = cadd(cmul(w0, sA[i][0]), cmul(w1, sA[i][1]));
                cpx t1 = cadd(cmul(w0, sA[i][1]), cmul(w1, sA[i][0]));
                w0 = cmul(sU[i][ni][0], t0);
                w1 = cmul(sU[i][ni][1], t1);
            }
            M[0][j] = w0; M[1][j] = w1;
        }
        const int n20 = e & 1;
        float o8[8];
        #pragma unroll
        for (int s = 0; s < 2; ++s) {
            #pragma unroll
            for (int j = 0; j < 2; ++j) {
                cpx d = cadd(cmul(M[0][j], sA[20][s]), cmul(M[1][j], sA[20][1^s]));
                cpx S = cmul(sU[20][n20][s], d);
                o8[s*4 + j*2 + 0] = S.re;
                o8[s*4 + j*2 + 1] = S.im;
            }
        }
        #pragma unroll
        for (int c = 0; c < 8; ++c) sSt[c][e] = o8[c];
    } else if (wv == 4) {
        // ---- all 64 prefix chains: lane -> (token k, closure-bit s) ----
        const int k = lane >> 1, s = lane & 1;
        const int v = pv;
        int n0 = (v >> 12) & 1;
        cpx w0 = cmul(sU[0][n0][0], sA[0][s]);
        cpx w1 = cmul(sU[0][n0][1], sA[0][1^s]);
        #pragma unroll
        for (int i = 1; i <= 12; ++i) {
            int ni = (v >> (12-i)) & 1;
            int sb = (i == 1) ? s : 0;
            cpx t0 = cadd(cmul(w0, sA[i][sb]),   cmul(w1, sA[i][1^sb]));
            cpx t1 = cadd(cmul(w0, sA[i][1^sb]), cmul(w1, sA[i][sb]));
            w0 = cmul(sU[i][ni][0], t0);
            w1 = cmul(sU[i][ni][1], t1);
        }
        sP4[k][s] = make_float4(w0.re, w0.im, w1.re, w1.im);
    }
    __syncthreads();

    // ---- register-load S components for this lane's 4 e's ----
    float sr[8][4];
    #pragma unroll
    for (int c = 0; c < 8; ++c) {
        float4 t = *(const float4*)&sSt[c][e0];
        sr[c][0] = t.x; sr[c][1] = t.y; sr[c][2] = t.z; sr[c][3] = t.w;
    }

    // ---- phase 2: 4 tokens per wave, batched ----
    float mags[4][4];
    float ls[4], lq[4];
    #pragma unroll
    for (int t = 0; t < 4; ++t) {
        const int k = wv*4 + t;
        const float4 p0 = sP4[k][0];
        const float4 p1 = sP4[k][1];
        float s_ = 0.f, q_ = 0.f;
        #pragma unroll
        for (int kk = 0; kk < 4; ++kk) {
            float re = p0.x*sr[0][kk] - p0.y*sr[1][kk]
                     + p0.z*sr[2][kk] - p0.w*sr[3][kk]
                     + p1.x*sr[4][kk] - p1.y*sr[5][kk]
                     + p1.z*sr[6][kk] - p1.w*sr[7][kk];
            float im = p0.x*sr[1][kk] + p0.y*sr[0][kk]
                     + p0.z*sr[3][kk] + p0.w*sr[2][kk]
                     + p1.x*sr[5][kk] + p1.y*sr[4][kk]
                     + p1.z*sr[7][kk] + p1.w*sr[6][kk];
            const float m = sqrtf(re*re + im*im);
            mags[t][kk] = m; s_ += m; q_ += m*m;
        }
        ls[t] = s_; lq[t] = q_;
    }

    // batched butterfly: 8 independent chains per level
    #pragma unroll
    for (int off = 32; off; off >>= 1) {
        #pragma unroll
        for (int t = 0; t < 4; ++t) {
            ls[t] += __shfl_xor(ls[t], off);
            lq[t] += __shfl_xor(lq[t], off);
        }
    }

    #pragma unroll
    for (int t = 0; t < 4; ++t) {
        const int tok = blockTok + wv*4 + t;
        const float mu = ls[t] * (1.0f/EMB);
        float var = lq[t] * (1.0f/EMB) - mu*mu;
        if (var < 0.f) var = 0.f;
        const float rs = rsqrtf(var + LN_EPS);
        if (tok < ntok) {
            float4 o;
            o.x = (mags[t][0]-mu)*rs*g4.x + b4.x;
            o.y = (mags[t][1]-mu)*rs*g4.y + b4.y;
            o.z = (mags[t][2]-mu)*rs*g4.z + b4.z;
            o.w = (mags[t][3]-mu)*rs*g4.w + b4.w;
            *(float4*)(out + tok*EMB + e0) = o;
        }
    }
}

extern "C" void kernel_launch(void* const* d_in, const int* in_sizes, int n_in,
                              void* d_out, int out_size, void* d_ws, size_t ws_size,
                              hipStream_t stream) {
    const int*   x     = (const int*)  d_in[0];
    const float* rp1   = (const float*)d_in[1];
    const float* rp2   = (const float*)d_in[2];
    const float* gamma = (const float*)d_in[3];
    const float* beta  = (const float*)d_in[4];
    float* out = (float*)d_out;
    const int ntok = in_sizes[0];                  // B*S = 16384
    const int tokPerBlock = 32;                    // 8 waves x 4 tokens
    const int nblocks = (ntok + tokPerBlock - 1) / tokPerBlock;
    qembed_one<<<nblocks, 512, 0, stream>>>(x, rp1, rp2, gamma, beta, out, ntok);
}